// Round 3
// baseline (598.706 us; speedup 1.0000x reference)
//
#include <hip/hip_runtime.h>

#define NB 16    // N*G
#define CD 64    // C == Cv
#define HD 2048  // H
#define LOG2E 1.44269504088896340736f

typedef unsigned short u16;
typedef __attribute__((ext_vector_type(8))) short s16x8;  // 8 bf16 (4 VGPRs)
typedef __attribute__((ext_vector_type(4))) float f32x4;  // MFMA C/D

extern "C" __device__ float __ocml_native_exp2_f32(float);
__device__ __forceinline__ float fexp2(float x){ return __ocml_native_exp2_f32(x); }

// ---- RNE split (prep kernels only) ----
__device__ __forceinline__ u16 f2bf(float x){
    unsigned u = __float_as_uint(x);
    u += 0x7FFFu + ((u >> 16) & 1u);
    return (u16)(u >> 16);
}
__device__ __forceinline__ float bf2f(u16 h){ return __uint_as_float(((unsigned)h) << 16); }
__device__ __forceinline__ void split2(float x, u16& h, u16& l){
    h = f2bf(x); l = f2bf(x - bf2f(h));
}
// ---- trunc split (hot path): hi = top16(x); lo = x - hi (exact); pack via v_perm ----
__device__ __forceinline__ float hi_f(float x){ return __uint_as_float(__float_as_uint(x) & 0xffff0000u); }
__device__ __forceinline__ unsigned pk2(float a, float b){   // low16 = trunc-bf16(a), high16 = trunc-bf16(b)
    return __builtin_amdgcn_perm(__float_as_uint(b), __float_as_uint(a), 0x07060302);
}

union Frag { uint4 q; s16x8 s; };
__device__ __forceinline__ s16x8 ld8(const u16* p){ Frag f; f.q = *(const uint4*)p; return f.s; }
__device__ __forceinline__ f32x4 mfma16(s16x8 a, s16x8 b, f32x4 c){
    return __builtin_amdgcn_mfma_f32_16x16x32_bf16(a, b, c, 0, 0, 0);
}
__device__ __forceinline__ f32x4 mm3(s16x8 ah, s16x8 al, s16x8 bh, s16x8 bl, f32x4 c){
    c = mfma16(ah, bh, c);
    c = mfma16(ah, bl, c);
    c = mfma16(al, bh, c);
    return c;
}
__device__ __forceinline__ f32x4 z4(){ f32x4 v = {0.f,0.f,0.f,0.f}; return v; }

// ---------------- prep kernels ----------------

__global__ void k_convert(const float* __restrict__ src, u16* __restrict__ dh,
                          u16* __restrict__ dl, int n4)
{
    int idx = blockIdx.x*256 + threadIdx.x;
    if (idx >= n4) return;
    float4 v = ((const float4*)src)[idx];
    ushort4 h, l;
    split2(v.x, h.x, l.x); split2(v.y, h.y, l.y);
    split2(v.z, h.z, l.z); split2(v.w, h.w, l.w);
    ((ushort4*)dh)[idx] = h;
    ((ushort4*)dl)[idx] = l;
}

// fp32 [bg][c=64][h=2048] -> bf16 hi/lo [bg][h][c=64]
__global__ void k_transpose(const float* __restrict__ src, u16* __restrict__ dh,
                            u16* __restrict__ dl)
{
    int bg = blockIdx.y, h0 = blockIdx.x*128, tid = threadIdx.x;
    __shared__ float ft[CD][132];
    #pragma unroll
    for (int k=0;k<8;k++){
        int flat = tid + 256*k;
        int c = flat >> 5, p = (flat & 31)*4;
        *(float4*)&ft[c][p] = *(const float4*)(src + ((size_t)bg*CD + c)*HD + h0 + p);
    }
    __syncthreads();
    int hl = tid >> 1, c0 = (tid & 1)*32;
    union { u16 u[32]; uint4 q[4]; } oh, ol;
    #pragma unroll
    for (int m=0;m<32;m++){
        float x = ft[c0+m][hl];
        u16 hh; split2(x, hh, ol.u[m]); oh.u[m] = hh;
    }
    size_t base = ((size_t)bg*HD + h0 + hl)*CD + c0;
    #pragma unroll
    for (int t=0;t<4;t++){
        *((uint4*)(dh + base) + t) = oh.q[t];
        *((uint4*)(dl + base) + t) = ol.q[t];
    }
}

// bias2[bg][j] = 0.5*beta*log2e*sum_c mu^2  (pre-scaled for exp2)
__global__ void k_bias(const float* __restrict__ mu, const float* __restrict__ beta,
                       float* __restrict__ bias2)
{
    int bg = blockIdx.y;
    int j  = blockIdx.x*256 + threadIdx.x;
    const float* m = mu + (size_t)bg*CD*HD + j;
    float s = 0.f;
    #pragma unroll
    for (int c=0;c<CD;c++){ float v = m[(size_t)c*HD]; s = fmaf(v, v, s); }
    bias2[(size_t)bg*HD + j] = 0.5f * beta[0] * LOG2E * s;
}

// ---------------- main MFMA kernels ----------------
// logit2_ij = a2*S_ij + bias2_j with S = q^T.z  (z2 terms cancel; row const drops in softmax)

// r[i] = sum_j exp2(a2*S+bias2_j). Block: 32 i-rows; waves split j within a 128-step.
__global__ __launch_bounds__(256,4) void k_rowsum(
    const u16* __restrict__ qTh, const u16* __restrict__ qTl,
    const u16* __restrict__ zTh, const u16* __restrict__ zTl,
    const float* __restrict__ bias2, const float* __restrict__ alpha,
    float* __restrict__ r)
{
    const int bg = blockIdx.y, i0 = blockIdx.x*32;
    const int tid = threadIdx.x, wave = tid>>6, lane = tid&63, ln = lane&15, quad = lane>>4;
    const float a2 = alpha[0]*LOG2E;
    __shared__ float rpart[4][32];

    s16x8 Ah[2][2], Al[2][2];     // resident q^T frags (rows i0..i0+31)
    #pragma unroll
    for (int mt=0;mt<2;mt++)
        #pragma unroll
        for (int ks=0;ks<2;ks++){
            size_t off = ((size_t)bg*HD + i0 + mt*16 + ln)*CD + ks*32 + quad*8;
            Ah[mt][ks] = ld8(qTh + off);
            Al[mt][ks] = ld8(qTl + off);
        }
    float racc[8];
    #pragma unroll
    for (int k=0;k<8;k++) racc[k] = 0.f;
    const float* bb = bias2 + (size_t)bg*HD;

    for (int j0=0;j0<HD;j0+=128){
        const int jw = j0 + wave*32;
        f32x4 acc[2][2];
        #pragma unroll
        for (int mt=0;mt<2;mt++){ acc[mt][0]=z4(); acc[mt][1]=z4(); }
        #pragma unroll
        for (int ks=0;ks<2;ks++){
            s16x8 Bh[2], Bl[2];
            #pragma unroll
            for (int nt=0;nt<2;nt++){
                size_t off = ((size_t)bg*HD + jw + nt*16 + ln)*CD + ks*32 + quad*8;
                Bh[nt] = ld8(zTh + off);
                Bl[nt] = ld8(zTl + off);
            }
            #pragma unroll
            for (int mt=0;mt<2;mt++)
                #pragma unroll
                for (int nt=0;nt<2;nt++)
                    acc[mt][nt] = mm3(Ah[mt][ks], Al[mt][ks], Bh[nt], Bl[nt], acc[mt][nt]);
        }
        float bj2[2];
        #pragma unroll
        for (int nt=0;nt<2;nt++) bj2[nt] = bb[jw + nt*16 + ln];
        #pragma unroll
        for (int mt=0;mt<2;mt++)
            #pragma unroll
            for (int nt=0;nt<2;nt++)
                #pragma unroll
                for (int rx=0;rx<4;rx++)
                    racc[mt*4+rx] += fexp2(fmaf(a2, acc[mt][nt][rx], bj2[nt]));
    }
    #pragma unroll
    for (int k=0;k<8;k++){
        float v = racc[k];
        v += __shfl_xor(v,1); v += __shfl_xor(v,2);
        v += __shfl_xor(v,4); v += __shfl_xor(v,8);
        racc[k] = v;
    }
    if (ln == 0){
        #pragma unroll
        for (int mt=0;mt<2;mt++)
            #pragma unroll
            for (int rx=0;rx<4;rx++)
                rpart[wave][mt*16 + quad*4 + rx] = racc[mt*4+rx];
    }
    __syncthreads();
    if (tid < 32)
        r[(size_t)bg*HD + i0 + tid] = rpart[0][tid]+rpart[1][tid]+rpart[2][tid]+rpart[3][tid];
}

// zeta update. Block: 32 j-cols; sweeps i (128/step, waves split i in phase A).
// Phase B: num[c][j] = sum_i q[c][i] w[i][j]; z^T overwritten in place (own rows only).
__global__ __launch_bounds__(256,4) void k_update(
    const u16* __restrict__ qTh, const u16* __restrict__ qTl,
    u16* zTh, u16* zTl,
    const u16* __restrict__ qNh, const u16* __restrict__ qNl,
    const float* __restrict__ bias2, const float* __restrict__ alpha,
    const float* __restrict__ r)
{
    const int bg = blockIdx.y, j0 = blockIdx.x*32;
    const int tid = threadIdx.x, wave = tid>>6, lane = tid&63, ln = lane&15, quad = lane>>4;
    const float a2 = alpha[0]*LOG2E;
    __shared__ u16 wlh[2][32*128], wll[2][32*128];   // [buf][j][i], 16B-block XOR swizzle
    __shared__ float denl[4][32];

    s16x8 Bh[2][2], Bl[2][2];     // resident z^T frags (own rows, read before overwrite)
    #pragma unroll
    for (int nt=0;nt<2;nt++)
        #pragma unroll
        for (int ks=0;ks<2;ks++){
            size_t off = ((size_t)bg*HD + j0 + nt*16 + ln)*CD + ks*32 + quad*8;
            Bh[nt][ks] = ld8(zTh + off);
            Bl[nt][ks] = ld8(zTl + off);
        }
    float bj2[2];
    #pragma unroll
    for (int nt=0;nt<2;nt++) bj2[nt] = bias2[(size_t)bg*HD + j0 + nt*16 + ln];

    f32x4 acc2[2] = {z4(), z4()};
    float den[2] = {0.f, 0.f};

    for (int s=0;s<HD/128;s++){
        const int is = s*128, buf = s&1;
        // ---- phase A: S tile (m = i: wave*32 + 2 mt; n = own j: 2 nt) ----
        f32x4 acc1[2][2];
        #pragma unroll
        for (int mt=0;mt<2;mt++){ acc1[mt][0]=z4(); acc1[mt][1]=z4(); }
        #pragma unroll
        for (int ks=0;ks<2;ks++){
            s16x8 Ah[2], Al[2];
            #pragma unroll
            for (int mt=0;mt<2;mt++){
                size_t off = ((size_t)bg*HD + is + wave*32 + mt*16 + ln)*CD + ks*32 + quad*8;
                Ah[mt] = ld8(qTh + off);
                Al[mt] = ld8(qTl + off);
            }
            #pragma unroll
            for (int mt=0;mt<2;mt++)
                #pragma unroll
                for (int nt=0;nt<2;nt++)
                    acc1[mt][nt] = mm3(Ah[mt], Al[mt], Bh[nt][ks], Bl[nt][ks], acc1[mt][nt]);
        }
        float ri[2][4];
        #pragma unroll
        for (int mt=0;mt<2;mt++){
            float4 rv = *(const float4*)(r + (size_t)bg*HD + is + wave*32 + mt*16 + quad*4);
            ri[mt][0] = __builtin_amdgcn_rcpf(rv.x); ri[mt][1] = __builtin_amdgcn_rcpf(rv.y);
            ri[mt][2] = __builtin_amdgcn_rcpf(rv.z); ri[mt][3] = __builtin_amdgcn_rcpf(rv.w);
        }
        #pragma unroll
        for (int mt=0;mt<2;mt++)
            #pragma unroll
            for (int nt=0;nt<2;nt++){
                float w[4], lo[4];
                #pragma unroll
                for (int rx=0;rx<4;rx++){
                    w[rx] = fexp2(fmaf(a2, acc1[mt][nt][rx], bj2[nt])) * ri[mt][rx];
                    lo[rx] = w[rx] - hi_f(w[rx]);
                }
                den[nt] += (w[0]+w[1]) + (w[2]+w[3]);
                int row = nt*16 + ln;                     // j-local
                int c4  = wave*32 + mt*16 + quad*4;       // i-local
                int b   = c4 >> 3;
                int off = row*128 + ((b ^ ln) << 3) + (c4 & 7);
                *(uint2*)&wlh[buf][off] = make_uint2(pk2(w[0],w[1]),  pk2(w[2],w[3]));
                *(uint2*)&wll[buf][off] = make_uint2(pk2(lo[0],lo[1]), pk2(lo[2],lo[3]));
            }
        __syncthreads();
        // ---- phase B: acc2[c][j] += qN.w  (m = c: wave*16; n = j: 2 nt2; k = i: 4 ks2) ----
        #pragma unroll
        for (int ks2=0;ks2<4;ks2++){
            s16x8 A2h, A2l, B2h[2], B2l[2];
            {
                size_t off = ((size_t)bg*CD + wave*16 + ln)*HD + is + ks2*32 + quad*8;
                A2h = ld8(qNh + off);
                A2l = ld8(qNl + off);
            }
            #pragma unroll
            for (int nt2=0;nt2<2;nt2++){
                int jl = nt2*16 + ln;
                int ob = jl*128 + (((ks2*4 + quad) ^ ln) << 3);
                B2h[nt2] = ld8(&wlh[buf][ob]);
                B2l[nt2] = ld8(&wll[buf][ob]);
            }
            #pragma unroll
            for (int nt2=0;nt2<2;nt2++)
                acc2[nt2] = mm3(A2h, A2l, B2h[nt2], B2l[nt2], acc2[nt2]);
        }
    }
    // denominator reduce: quads via shfl, waves via LDS
    #pragma unroll
    for (int nt=0;nt<2;nt++){
        float v = den[nt];
        v += __shfl_xor(v,16); v += __shfl_xor(v,32);
        if (quad == 0) denl[wave][nt*16 + ln] = v;
    }
    __syncthreads();
    #pragma unroll
    for (int nt2=0;nt2<2;nt2++){
        int jl = nt2*16 + ln;
        float dinv = __builtin_amdgcn_rcpf(denl[0][jl]+denl[1][jl]+denl[2][jl]+denl[3][jl]);
        float v[4], lo[4];
        #pragma unroll
        for (int rx=0;rx<4;rx++){
            v[rx] = acc2[nt2][rx] * dinv;
            lo[rx] = v[rx] - hi_f(v[rx]);
        }
        size_t off = ((size_t)bg*HD + j0 + jl)*CD + wave*16 + quad*4;
        *(uint2*)(zTh + off) = make_uint2(pk2(v[0],v[1]),  pk2(v[2],v[3]));
        *(uint2*)(zTl + off) = make_uint2(pk2(lo[0],lo[1]), pk2(lo[2],lo[3]));
    }
}

// final: out[c][i] = (sum_j e_ij mu_cj) / (sum_j e_ij). Block: 32 i; sweeps j (128/step).
__global__ __launch_bounds__(256,4) void k_final(
    const u16* __restrict__ qTh, const u16* __restrict__ qTl,
    const u16* __restrict__ zTh, const u16* __restrict__ zTl,
    const u16* __restrict__ muh, const u16* __restrict__ mul_,
    const float* __restrict__ bias2, const float* __restrict__ alpha,
    float* __restrict__ out)
{
    const int bg = blockIdx.y, i0 = blockIdx.x*32;
    const int tid = threadIdx.x, wave = tid>>6, lane = tid&63, ln = lane&15, quad = lane>>4;
    const float a2 = alpha[0]*LOG2E;
    __shared__ u16 elh[2][32*128], ell[2][32*128];   // [buf][i][j], swizzled
    __shared__ float rl[4][32];

    s16x8 Bh[2][2], Bl[2][2];     // resident q^T frags (rows i0..i0+31) as n operand
    #pragma unroll
    for (int nt=0;nt<2;nt++)
        #pragma unroll
        for (int ks=0;ks<2;ks++){
            size_t off = ((size_t)bg*HD + i0 + nt*16 + ln)*CD + ks*32 + quad*8;
            Bh[nt][ks] = ld8(qTh + off);
            Bl[nt][ks] = ld8(qTl + off);
        }
    f32x4 acc2[2] = {z4(), z4()};
    float racc[2] = {0.f, 0.f};

    for (int s=0;s<HD/128;s++){
        const int js = s*128, buf = s&1;
        // ---- phase A: S'[j][i] (m = j: wave*32 + 2 mt; n = i: 2 nt) ----
        f32x4 acc1[2][2];
        #pragma unroll
        for (int mt=0;mt<2;mt++){ acc1[mt][0]=z4(); acc1[mt][1]=z4(); }
        #pragma unroll
        for (int ks=0;ks<2;ks++){
            s16x8 Ah[2], Al[2];
            #pragma unroll
            for (int mt=0;mt<2;mt++){
                size_t off = ((size_t)bg*HD + js + wave*32 + mt*16 + ln)*CD + ks*32 + quad*8;
                Ah[mt] = ld8(zTh + off);
                Al[mt] = ld8(zTl + off);
            }
            #pragma unroll
            for (int mt=0;mt<2;mt++)
                #pragma unroll
                for (int nt=0;nt<2;nt++)
                    acc1[mt][nt] = mm3(Ah[mt], Al[mt], Bh[nt][ks], Bl[nt][ks], acc1[mt][nt]);
        }
        float4 bj4[2];
        #pragma unroll
        for (int mt=0;mt<2;mt++)
            bj4[mt] = *(const float4*)(bias2 + (size_t)bg*HD + js + wave*32 + mt*16 + quad*4);
        #pragma unroll
        for (int mt=0;mt<2;mt++)
            #pragma unroll
            for (int nt=0;nt<2;nt++){
                float e[4], lo[4];
                const float* bp = &bj4[mt].x;
                #pragma unroll
                for (int rx=0;rx<4;rx++){
                    e[rx] = fexp2(fmaf(a2, acc1[mt][nt][rx], bp[rx]));
                    lo[rx] = e[rx] - hi_f(e[rx]);
                }
                racc[nt] += (e[0]+e[1]) + (e[2]+e[3]);
                int row = nt*16 + ln;                     // i-local
                int jj  = wave*32 + mt*16 + quad*4;       // j-local
                int b   = jj >> 3;
                int off = row*128 + ((b ^ ln) << 3) + (jj & 7);
                *(uint2*)&elh[buf][off] = make_uint2(pk2(e[0],e[1]),  pk2(e[2],e[3]));
                *(uint2*)&ell[buf][off] = make_uint2(pk2(lo[0],lo[1]), pk2(lo[2],lo[3]));
            }
        __syncthreads();
        // ---- phase B: acc2[c][i] += mu.e^T (m = c: wave*16; n = i: 2 nt2; k = j: 4 ks2) ----
        #pragma unroll
        for (int ks2=0;ks2<4;ks2++){
            s16x8 A2h, A2l, B2h[2], B2l[2];
            {
                size_t off = ((size_t)bg*CD + wave*16 + ln)*HD + js + ks2*32 + quad*8;
                A2h = ld8(muh + off);
                A2l = ld8(mul_ + off);
            }
            #pragma unroll
            for (int nt2=0;nt2<2;nt2++){
                int il = nt2*16 + ln;
                int ob = il*128 + (((ks2*4 + quad) ^ ln) << 3);
                B2h[nt2] = ld8(&elh[buf][ob]);
                B2l[nt2] = ld8(&ell[buf][ob]);
            }
            #pragma unroll
            for (int nt2=0;nt2<2;nt2++)
                acc2[nt2] = mm3(A2h, A2l, B2h[nt2], B2l[nt2], acc2[nt2]);
        }
    }
    #pragma unroll
    for (int nt=0;nt<2;nt++){
        float v = racc[nt];
        v += __shfl_xor(v,16); v += __shfl_xor(v,32);
        if (quad == 0) rl[wave][nt*16 + ln] = v;
    }
    __syncthreads();
    #pragma unroll
    for (int nt2=0;nt2<2;nt2++){
        int il = nt2*16 + ln;
        float rinv = __builtin_amdgcn_rcpf(rl[0][il]+rl[1][il]+rl[2][il]+rl[3][il]);
        #pragma unroll
        for (int rx=0;rx<4;rx++)
            out[((size_t)bg*CD + wave*16 + quad*4 + rx)*HD + i0 + il] = acc2[nt2][rx] * rinv;
    }
}

extern "C" void kernel_launch(void* const* d_in, const int* in_sizes, int n_in,
                              void* d_out, int out_size, void* d_ws, size_t ws_size,
                              hipStream_t stream)
{
    (void)in_sizes; (void)n_in; (void)out_size; (void)ws_size;
    const float* q     = (const float*)d_in[0];
    const float* zeta  = (const float*)d_in[1];
    const float* alpha = (const float*)d_in[2];
    const float* mu    = (const float*)d_in[3];
    const float* beta  = (const float*)d_in[4];
    float* out = (float*)d_out;

    const size_t SZ = (size_t)NB*HD*CD;
    u16* qTh = (u16*)d_ws;
    u16* qTl = qTh + 1*SZ;
    u16* zTh = qTh + 2*SZ;
    u16* zTl = qTh + 3*SZ;
    u16* qNh = qTh + 4*SZ;
    u16* qNl = qTh + 5*SZ;
    u16* muh = qTh + 6*SZ;
    u16* mul_= qTh + 7*SZ;
    float* bias2 = (float*)(qTh + 8*SZ);
    float* r     = bias2 + (size_t)NB*HD;

    dim3 blk(256,1,1);
    int n4 = (int)(SZ/4);
    k_convert  <<<dim3(n4/256), blk, 0, stream>>>(q,  qNh, qNl, n4);
    k_convert  <<<dim3(n4/256), blk, 0, stream>>>(mu, muh, mul_, n4);
    k_transpose<<<dim3(HD/128, NB), blk, 0, stream>>>(q,    qTh, qTl);
    k_transpose<<<dim3(HD/128, NB), blk, 0, stream>>>(zeta, zTh, zTl);
    k_bias     <<<dim3(HD/256, NB), blk, 0, stream>>>(mu, beta, bias2);

    k_rowsum<<<dim3(HD/32, NB), blk, 0, stream>>>(qTh,qTl,zTh,zTl,bias2,alpha,r);
    k_update<<<dim3(HD/32, NB), blk, 0, stream>>>(qTh,qTl,zTh,zTl,qNh,qNl,bias2,alpha,r);
    k_rowsum<<<dim3(HD/32, NB), blk, 0, stream>>>(qTh,qTl,zTh,zTl,bias2,alpha,r);
    k_update<<<dim3(HD/32, NB), blk, 0, stream>>>(qTh,qTl,zTh,zTl,qNh,qNl,bias2,alpha,r);
    k_final <<<dim3(HD/32, NB), blk, 0, stream>>>(qTh,qTl,zTh,zTl,muh,mul_,bias2,alpha,out);
}

// Round 4
// 536.185 us; speedup vs baseline: 1.1166x; 1.1166x over previous
//
#include <hip/hip_runtime.h>

#define NB 16    // N*G
#define CD 64    // C == Cv
#define HD 2048  // H
#define LOG2E 1.44269504088896340736f

typedef unsigned short u16;
typedef __attribute__((ext_vector_type(8))) short s16x8;    // 8 bf16 (4 VGPRs)
typedef __attribute__((ext_vector_type(16))) float f32x16;  // 32x32 MFMA C/D

extern "C" __device__ float __ocml_native_exp2_f32(float);
__device__ __forceinline__ float fexp2(float x){ return __ocml_native_exp2_f32(x); }

// ---- RNE split (prep kernels only) ----
__device__ __forceinline__ u16 f2bf(float x){
    unsigned u = __float_as_uint(x);
    u += 0x7FFFu + ((u >> 16) & 1u);
    return (u16)(u >> 16);
}
__device__ __forceinline__ float bf2f(u16 h){ return __uint_as_float(((unsigned)h) << 16); }
__device__ __forceinline__ void split2(float x, u16& h, u16& l){
    h = f2bf(x); l = f2bf(x - bf2f(h));
}
// ---- trunc split (hot path) ----
__device__ __forceinline__ float hi_f(float x){ return __uint_as_float(__float_as_uint(x) & 0xffff0000u); }
__device__ __forceinline__ unsigned pk2(float a, float b){  // low16=trunc-bf16(a), high16=trunc-bf16(b)
    return __builtin_amdgcn_perm(__float_as_uint(b), __float_as_uint(a), 0x07060302);
}

union Frag { uint4 q; s16x8 s; };
__device__ __forceinline__ s16x8 ld8(const u16* p){ Frag f; f.q = *(const uint4*)p; return f.s; }
__device__ __forceinline__ f32x16 mfma32(s16x8 a, s16x8 b, f32x16 c){
    return __builtin_amdgcn_mfma_f32_32x32x16_bf16(a, b, c, 0, 0, 0);
}
__device__ __forceinline__ f32x16 mm3(s16x8 ah, s16x8 al, s16x8 bh, s16x8 bl, f32x16 c){
    c = mfma32(ah, bh, c);
    c = mfma32(ah, bl, c);
    c = mfma32(al, bh, c);
    return c;
}
__device__ __forceinline__ f32x16 z16(){ f32x16 v = {0.f}; for(int i=0;i<16;i++) v[i]=0.f; return v; }

// XCD-aware block remap: grid = 512 (32 tiles x 16 bg); same-bg blocks cluster per XCD.
__device__ __forceinline__ void remap(int lin, int& bg, int& t0){
    int xcd  = lin & 7;
    int slot = lin >> 3;            // 0..63
    bg = xcd + 8*(slot >> 5);       // 2 bgs per XCD, temporally grouped
    t0 = (slot & 31) * 64;
}

// ---------------- prep kernels ----------------

__global__ void k_convert(const float* __restrict__ src, u16* __restrict__ dh,
                          u16* __restrict__ dl, int n4)
{
    int idx = blockIdx.x*256 + threadIdx.x;
    if (idx >= n4) return;
    float4 v = ((const float4*)src)[idx];
    ushort4 h, l;
    split2(v.x, h.x, l.x); split2(v.y, h.y, l.y);
    split2(v.z, h.z, l.z); split2(v.w, h.w, l.w);
    ((ushort4*)dh)[idx] = h;
    ((ushort4*)dl)[idx] = l;
}

// fp32 [bg][c=64][h=2048] -> bf16 hi/lo [bg][h][c=64]
__global__ void k_transpose(const float* __restrict__ src, u16* __restrict__ dh,
                            u16* __restrict__ dl)
{
    int bg = blockIdx.y, h0 = blockIdx.x*128, tid = threadIdx.x;
    __shared__ float ft[CD][132];
    #pragma unroll
    for (int k=0;k<8;k++){
        int flat = tid + 256*k;
        int c = flat >> 5, p = (flat & 31)*4;
        *(float4*)&ft[c][p] = *(const float4*)(src + ((size_t)bg*CD + c)*HD + h0 + p);
    }
    __syncthreads();
    int hl = tid >> 1, c0 = (tid & 1)*32;
    union { u16 u[32]; uint4 q[4]; } oh, ol;
    #pragma unroll
    for (int m=0;m<32;m++){
        float x = ft[c0+m][hl];
        u16 hh; split2(x, hh, ol.u[m]); oh.u[m] = hh;
    }
    size_t base = ((size_t)bg*HD + h0 + hl)*CD + c0;
    #pragma unroll
    for (int t=0;t<4;t++){
        *((uint4*)(dh + base) + t) = oh.q[t];
        *((uint4*)(dl + base) + t) = ol.q[t];
    }
}

// bias2[bg][j] = 0.5*beta*log2e*sum_c mu^2  (pre-scaled for exp2)
__global__ void k_bias(const float* __restrict__ mu, const float* __restrict__ beta,
                       float* __restrict__ bias2)
{
    int bg = blockIdx.y;
    int j  = blockIdx.x*256 + threadIdx.x;
    const float* m = mu + (size_t)bg*CD*HD + j;
    float s = 0.f;
    #pragma unroll
    for (int c=0;c<CD;c++){ float v = m[(size_t)c*HD]; s = fmaf(v, v, s); }
    bias2[(size_t)bg*HD + j] = 0.5f * beta[0] * LOG2E * s;
}

// ---------------- main MFMA kernels (32x32x16) ----------------
// C/D layout: col=lane&31, row=(reg&3)+8*(reg>>2)+4*(lane>>5)
// A[m][k]: m=lane&31, k=(lane>>5)*8+j ; B[k][n]: n=lane&31, k=(lane>>5)*8+j

// r[i] = sum_j exp2(a2*S + bias2_j). Block: 64 i-rows resident; sweeps j (128/step, waves split j).
__global__ __launch_bounds__(256,2) void k_rowsum(
    const u16* __restrict__ qTh, const u16* __restrict__ qTl,
    const u16* __restrict__ zTh, const u16* __restrict__ zTl,
    const float* __restrict__ bias2, const float* __restrict__ alpha,
    float* __restrict__ r)
{
    int bg, i0; remap(blockIdx.x, bg, i0);
    const int tid = threadIdx.x, wave = tid>>6, lane = tid&63, l31 = lane&31, half = lane>>5;
    const float a2 = alpha[0]*LOG2E;
    __shared__ float rpart[4][64];

    s16x8 Ah[2][4], Al[2][4];     // resident q^T: rows i0 + mt*32 + l31
    #pragma unroll
    for (int mt=0;mt<2;mt++)
        #pragma unroll
        for (int ks=0;ks<4;ks++){
            size_t off = ((size_t)bg*HD + i0 + mt*32 + l31)*CD + ks*16 + half*8;
            Ah[mt][ks] = ld8(qTh + off);
            Al[mt][ks] = ld8(qTl + off);
        }
    float racc[2][16];
    #pragma unroll
    for (int mt=0;mt<2;mt++)
        #pragma unroll
        for (int rx=0;rx<16;rx++) racc[mt][rx] = 0.f;

    s16x8 Bh[2][4], Bl[2][4];     // double-buffered streamed z^T frags
    #pragma unroll
    for (int ks=0;ks<4;ks++){
        size_t off = ((size_t)bg*HD + wave*32 + l31)*CD + ks*16 + half*8;
        Bh[0][ks] = ld8(zTh + off);
        Bl[0][ks] = ld8(zTl + off);
    }
    #pragma unroll 2
    for (int s=0;s<HD/128;s++){
        const int jw = s*128 + wave*32, cur = s&1, nxt = cur^1;
        f32x16 acc[2] = {z16(), z16()};
        #pragma unroll
        for (int ks=0;ks<4;ks++)
            #pragma unroll
            for (int mt=0;mt<2;mt++)
                acc[mt] = mm3(Ah[mt][ks], Al[mt][ks], Bh[cur][ks], Bl[cur][ks], acc[mt]);
        if (s+1 < HD/128){
            #pragma unroll
            for (int ks=0;ks<4;ks++){
                size_t off = ((size_t)bg*HD + (s+1)*128 + wave*32 + l31)*CD + ks*16 + half*8;
                Bh[nxt][ks] = ld8(zTh + off);
                Bl[nxt][ks] = ld8(zTl + off);
            }
        }
        float bj = bias2[(size_t)bg*HD + jw + l31];
        #pragma unroll
        for (int mt=0;mt<2;mt++)
            #pragma unroll
            for (int rx=0;rx<16;rx++)
                racc[mt][rx] += fexp2(fmaf(a2, acc[mt][rx], bj));
    }
    // row-sum: reduce over 32 cols (lanes within a half)
    #pragma unroll
    for (int mt=0;mt<2;mt++)
        #pragma unroll
        for (int rx=0;rx<16;rx++){
            float v = racc[mt][rx];
            v += __shfl_xor(v,1); v += __shfl_xor(v,2);
            v += __shfl_xor(v,4); v += __shfl_xor(v,8); v += __shfl_xor(v,16);
            racc[mt][rx] = v;
        }
    if (l31 == 0){
        #pragma unroll
        for (int mt=0;mt<2;mt++)
            #pragma unroll
            for (int rx=0;rx<16;rx++)
                rpart[wave][mt*32 + (rx&3) + 8*(rx>>2) + 4*half] = racc[mt][rx];
    }
    __syncthreads();
    if (tid < 64)
        r[(size_t)bg*HD + i0 + tid] = rpart[0][tid]+rpart[1][tid]+rpart[2][tid]+rpart[3][tid];
}

// zeta update. Block: 64 j-cols resident; sweeps i (128/step, waves split i in phase A).
// Phase B: num[c][j] = sum_i q[c][i] w[i][j]; z^T overwritten in place (own rows only).
__global__ __launch_bounds__(256,2) void k_update(
    const u16* __restrict__ qTh, const u16* __restrict__ qTl,
    u16* zTh, u16* zTl,
    const u16* __restrict__ qNh, const u16* __restrict__ qNl,
    const float* __restrict__ bias2, const float* __restrict__ alpha,
    const float* __restrict__ r)
{
    int bg, j0; remap(blockIdx.x, bg, j0);
    const int tid = threadIdx.x, wave = tid>>6, lane = tid&63, l31 = lane&31, half = lane>>5;
    const int cm = (wave&1)*32, jn = (wave>>1)*32;
    const float a2 = alpha[0]*LOG2E;
    __shared__ u16 wlh[2][64*128], wll[2][64*128];   // [buf][j][i], 16B-block XOR swizzle
    __shared__ float denl[4][64];

    s16x8 Bh[2][4], Bl[2][4];     // resident z^T (own rows; read before any overwrite)
    #pragma unroll
    for (int nt=0;nt<2;nt++)
        #pragma unroll
        for (int ks=0;ks<4;ks++){
            size_t off = ((size_t)bg*HD + j0 + nt*32 + l31)*CD + ks*16 + half*8;
            Bh[nt][ks] = ld8(zTh + off);
            Bl[nt][ks] = ld8(zTl + off);
        }
    float bj[2];
    #pragma unroll
    for (int nt=0;nt<2;nt++) bj[nt] = bias2[(size_t)bg*HD + j0 + nt*32 + l31];

    f32x16 acc2 = z16();
    float den[2] = {0.f, 0.f};

    s16x8 Ah[2][4], Al[2][4];     // double-buffered streamed q^T frags
    #pragma unroll
    for (int ks=0;ks<4;ks++){
        size_t off = ((size_t)bg*HD + wave*32 + l31)*CD + ks*16 + half*8;
        Ah[0][ks] = ld8(qTh + off);
        Al[0][ks] = ld8(qTl + off);
    }
    #pragma unroll 2
    for (int s=0;s<HD/128;s++){
        const int is = s*128, buf = s&1, cur = s&1, nxt = cur^1;
        // ---- phase A: S tile (m = i: wave*32; n = own j: 2 nt) ----
        f32x16 acc1[2] = {z16(), z16()};
        #pragma unroll
        for (int ks=0;ks<4;ks++)
            #pragma unroll
            for (int nt=0;nt<2;nt++)
                acc1[nt] = mm3(Ah[cur][ks], Al[cur][ks], Bh[nt][ks], Bl[nt][ks], acc1[nt]);
        if (s+1 < HD/128){
            #pragma unroll
            for (int ks=0;ks<4;ks++){
                size_t off = ((size_t)bg*HD + (s+1)*128 + wave*32 + l31)*CD + ks*16 + half*8;
                Ah[nxt][ks] = ld8(qTh + off);
                Al[nxt][ks] = ld8(qTl + off);
            }
        }
        float4 rv[4];
        #pragma unroll
        for (int rq=0;rq<4;rq++)
            rv[rq] = *(const float4*)(r + (size_t)bg*HD + is + wave*32 + rq*8 + 4*half);
        #pragma unroll
        for (int nt=0;nt<2;nt++){
            #pragma unroll
            for (int rq=0;rq<4;rq++){
                const float* rp = &rv[rq].x;
                float w[4], lo[4];
                #pragma unroll
                for (int rx=0;rx<4;rx++){
                    w[rx] = fexp2(fmaf(a2, acc1[nt][rq*4+rx], bj[nt]))
                            * __builtin_amdgcn_rcpf(rp[rx]);
                    lo[rx] = w[rx] - hi_f(w[rx]);
                }
                den[nt] += (w[0]+w[1]) + (w[2]+w[3]);
                int off = (nt*32 + l31)*128 + (((wave*4+rq) ^ (l31&15))<<3) + 4*half;
                *(uint2*)&wlh[buf][off] = make_uint2(pk2(w[0],w[1]),  pk2(w[2],w[3]));
                *(uint2*)&wll[buf][off] = make_uint2(pk2(lo[0],lo[1]), pk2(lo[2],lo[3]));
            }
        }
        __syncthreads();
        // ---- phase B: acc2[c][j] += qN.w  (m = c: cm; n = j: jn; k = i: 8 ks2) ----
        #pragma unroll
        for (int ks2=0;ks2<8;ks2++){
            size_t offA = ((size_t)bg*CD + cm + l31)*HD + is + ks2*16 + half*8;
            s16x8 A2h = ld8(qNh + offA);
            s16x8 A2l = ld8(qNl + offA);
            int offB = (jn + l31)*128 + (((ks2*2 + half) ^ (l31&15))<<3);
            s16x8 B2h = ld8(&wlh[buf][offB]);
            s16x8 B2l = ld8(&wll[buf][offB]);
            acc2 = mm3(A2h, A2l, B2h, B2l, acc2);
        }
    }
    // denominator: per-lane has 16 i-rows summed into den[nt] at col j = nt*32+l31
    #pragma unroll
    for (int nt=0;nt<2;nt++){
        float v = den[nt];
        v += __shfl_xor(v,32);                // add other half's rows (same col)
        if (half == 0) denl[wave][nt*32 + l31] = v;
    }
    __syncthreads();
    {
        int jl = jn + l31;
        float dinv = __builtin_amdgcn_rcpf(denl[0][jl]+denl[1][jl]+denl[2][jl]+denl[3][jl]);
        #pragma unroll
        for (int rq=0;rq<4;rq++){
            float v[4], lo[4];
            #pragma unroll
            for (int rx=0;rx<4;rx++){
                v[rx] = acc2[rq*4+rx] * dinv;
                lo[rx] = v[rx] - hi_f(v[rx]);
            }
            size_t off = ((size_t)bg*HD + j0 + jl)*CD + cm + rq*8 + 4*half;
            *(uint2*)(zTh + off) = make_uint2(pk2(v[0],v[1]),  pk2(v[2],v[3]));
            *(uint2*)(zTl + off) = make_uint2(pk2(lo[0],lo[1]), pk2(lo[2],lo[3]));
        }
    }
}

// final: out[c][i] = (sum_j e_ij mu_cj) / (sum_j e_ij). Block: 64 i resident; sweeps j.
__global__ __launch_bounds__(256,2) void k_final(
    const u16* __restrict__ qTh, const u16* __restrict__ qTl,
    const u16* __restrict__ zTh, const u16* __restrict__ zTl,
    const u16* __restrict__ muh, const u16* __restrict__ mul_,
    const float* __restrict__ bias2, const float* __restrict__ alpha,
    float* __restrict__ out)
{
    int bg, i0; remap(blockIdx.x, bg, i0);
    const int tid = threadIdx.x, wave = tid>>6, lane = tid&63, l31 = lane&31, half = lane>>5;
    const int cm = (wave&1)*32, in_ = (wave>>1)*32;
    const float a2 = alpha[0]*LOG2E;
    __shared__ u16 elh[2][64*128], ell[2][64*128];   // [buf][i][j], swizzled
    __shared__ float rl[4][64];

    s16x8 Bh[2][4], Bl[2][4];     // resident q^T (n = i own rows)
    #pragma unroll
    for (int nt=0;nt<2;nt++)
        #pragma unroll
        for (int ks=0;ks<4;ks++){
            size_t off = ((size_t)bg*HD + i0 + nt*32 + l31)*CD + ks*16 + half*8;
            Bh[nt][ks] = ld8(qTh + off);
            Bl[nt][ks] = ld8(qTl + off);
        }
    f32x16 acc2 = z16();
    float racc[2] = {0.f, 0.f};

    s16x8 Ah[2][4], Al[2][4];     // double-buffered streamed z^T frags (m = j)
    #pragma unroll
    for (int ks=0;ks<4;ks++){
        size_t off = ((size_t)bg*HD + wave*32 + l31)*CD + ks*16 + half*8;
        Ah[0][ks] = ld8(zTh + off);
        Al[0][ks] = ld8(zTl + off);
    }
    #pragma unroll 2
    for (int s=0;s<HD/128;s++){
        const int js = s*128, buf = s&1, cur = s&1, nxt = cur^1;
        // ---- phase A: S'[j][i] (m = j: wave*32; n = i: 2 nt) ----
        f32x16 acc1[2] = {z16(), z16()};
        #pragma unroll
        for (int ks=0;ks<4;ks++)
            #pragma unroll
            for (int nt=0;nt<2;nt++)
                acc1[nt] = mm3(Ah[cur][ks], Al[cur][ks], Bh[nt][ks], Bl[nt][ks], acc1[nt]);
        if (s+1 < HD/128){
            #pragma unroll
            for (int ks=0;ks<4;ks++){
                size_t off = ((size_t)bg*HD + (s+1)*128 + wave*32 + l31)*CD + ks*16 + half*8;
                Ah[nxt][ks] = ld8(zTh + off);
                Al[nxt][ks] = ld8(zTl + off);
            }
        }
        float4 bv[4];
        #pragma unroll
        for (int rq=0;rq<4;rq++)
            bv[rq] = *(const float4*)(bias2 + (size_t)bg*HD + js + wave*32 + rq*8 + 4*half);
        #pragma unroll
        for (int nt=0;nt<2;nt++){
            #pragma unroll
            for (int rq=0;rq<4;rq++){
                const float* bp = &bv[rq].x;
                float e[4], lo[4];
                #pragma unroll
                for (int rx=0;rx<4;rx++){
                    e[rx] = fexp2(fmaf(a2, acc1[nt][rq*4+rx], bp[rx]));
                    lo[rx] = e[rx] - hi_f(e[rx]);
                }
                racc[nt] += (e[0]+e[1]) + (e[2]+e[3]);
                int off = (nt*32 + l31)*128 + (((wave*4+rq) ^ (l31&15))<<3) + 4*half;
                *(uint2*)&elh[buf][off] = make_uint2(pk2(e[0],e[1]),  pk2(e[2],e[3]));
                *(uint2*)&ell[buf][off] = make_uint2(pk2(lo[0],lo[1]), pk2(lo[2],lo[3]));
            }
        }
        __syncthreads();
        // ---- phase B: acc2[c][i] += mu.e^T  (m = c: cm; n = i: in_; k = j: 8 ks2) ----
        #pragma unroll
        for (int ks2=0;ks2<8;ks2++){
            size_t offA = ((size_t)bg*CD + cm + l31)*HD + js + ks2*16 + half*8;
            s16x8 A2h = ld8(muh + offA);
            s16x8 A2l = ld8(mul_ + offA);
            int offB = (in_ + l31)*128 + (((ks2*2 + half) ^ (l31&15))<<3);
            s16x8 B2h = ld8(&elh[buf][offB]);
            s16x8 B2l = ld8(&ell[buf][offB]);
            acc2 = mm3(A2h, A2l, B2h, B2l, acc2);
        }
    }
    #pragma unroll
    for (int nt=0;nt<2;nt++){
        float v = racc[nt];
        v += __shfl_xor(v,32);
        if (half == 0) rl[wave][nt*32 + l31] = v;
    }
    __syncthreads();
    {
        int il = in_ + l31;
        float rinv = __builtin_amdgcn_rcpf(rl[0][il]+rl[1][il]+rl[2][il]+rl[3][il]);
        #pragma unroll
        for (int rx=0;rx<16;rx++){
            int c = cm + (rx&3) + 8*(rx>>2) + 4*half;
            out[((size_t)bg*CD + c)*HD + i0 + il] = acc2[rx] * rinv;
        }
    }
}

extern "C" void kernel_launch(void* const* d_in, const int* in_sizes, int n_in,
                              void* d_out, int out_size, void* d_ws, size_t ws_size,
                              hipStream_t stream)
{
    (void)in_sizes; (void)n_in; (void)out_size; (void)ws_size;
    const float* q     = (const float*)d_in[0];
    const float* zeta  = (const float*)d_in[1];
    const float* alpha = (const float*)d_in[2];
    const float* mu    = (const float*)d_in[3];
    const float* beta  = (const float*)d_in[4];
    float* out = (float*)d_out;

    const size_t SZ = (size_t)NB*HD*CD;
    u16* qTh = (u16*)d_ws;
    u16* qTl = qTh + 1*SZ;
    u16* zTh = qTh + 2*SZ;
    u16* zTl = qTh + 3*SZ;
    u16* qNh = qTh + 4*SZ;
    u16* qNl = qTh + 5*SZ;
    u16* muh = qTh + 6*SZ;
    u16* mul_= qTh + 7*SZ;
    float* bias2 = (float*)(qTh + 8*SZ);
    float* r     = bias2 + (size_t)NB*HD;

    dim3 blk(256,1,1);
    int n4 = (int)(SZ/4);
    k_convert  <<<dim3(n4/256), blk, 0, stream>>>(q,  qNh, qNl, n4);
    k_convert  <<<dim3(n4/256), blk, 0, stream>>>(mu, muh, mul_, n4);
    k_transpose<<<dim3(HD/128, NB), blk, 0, stream>>>(q,    qTh, qTl);
    k_transpose<<<dim3(HD/128, NB), blk, 0, stream>>>(zeta, zTh, zTl);
    k_bias     <<<dim3(HD/256, NB), blk, 0, stream>>>(mu, beta, bias2);

    k_rowsum<<<dim3(512), blk, 0, stream>>>(qTh,qTl,zTh,zTl,bias2,alpha,r);
    k_update<<<dim3(512), blk, 0, stream>>>(qTh,qTl,zTh,zTl,qNh,qNl,bias2,alpha,r);
    k_rowsum<<<dim3(512), blk, 0, stream>>>(qTh,qTl,zTh,zTl,bias2,alpha,r);
    k_update<<<dim3(512), blk, 0, stream>>>(qTh,qTl,zTh,zTl,qNh,qNl,bias2,alpha,r);
    k_final <<<dim3(512), blk, 0, stream>>>(qTh,qTl,zTh,zTl,muh,mul_,bias2,alpha,out);
}